// Round 15
// baseline (2171.714 us; speedup 1.0000x reference)
//
#include <hip/hip_runtime.h>
#include <hip/hip_bf16.h>
#include <hip/hip_cooperative_groups.h>

namespace cg = cooperative_groups;

#define DMdl 512
#define DIn  1024
#define DSn  16
#define DRn  32
#define NLa  4
#define BSz  16
#define LSq  200
#define CCl  200
#define MROWS (BSz*LSq)   // 3200
#define TCH  50           // scan chunk length (200 = 4*50)
#define XSTR 68           // padded xdb row stride in LDS (floats)
#define NBY  25           // 3200/128 row-bands
#define BANDG 32          // NBY padded to XCD groups
#define SCANV 1024        // scan virtual-block space

typedef __hip_bfloat16 bf16;
typedef unsigned short ushort;
typedef unsigned int uint;
typedef short short8 __attribute__((ext_vector_type(8)));
typedef float f32x4 __attribute__((ext_vector_type(4)));

__device__ __forceinline__ float b2f(bf16 v) { return __bfloat162float(v); }
__device__ __forceinline__ short f2s(float v) {
  bf16 h = __float2bfloat16(v);
  return *reinterpret_cast<short*>(&h);
}
__device__ __forceinline__ float lo_f(uint v) { return __uint_as_float(v << 16); }
__device__ __forceinline__ float hi_f(uint v) { return __uint_as_float(v & 0xFFFF0000u); }
__device__ __forceinline__ uint bbits(float v) { return (uint)(ushort)f2s(v); }

template<int CTRL>
__device__ __forceinline__ float dpp_add(float c) {
  int t = __builtin_amdgcn_update_dpp(0, __float_as_int(c), CTRL, 0xF, 0xF, true);
  return c + __int_as_float(t);
}

__device__ __forceinline__ bool probe_is_f32(const void* lnw) {
  const unsigned short* p = (const unsigned short*)lnw;
  return (p[0] == 0) && (p[2] == 0);
}
__device__ __forceinline__ float ld_in(const void* p, int i, bool f32) {
  return f32 ? ((const float*)p)[i] : b2f(((const bf16*)p)[i]);
}
__device__ __forceinline__ short ld_inb(const void* p, int i, bool f32) {
  if (f32) return f2s(((const float*)p)[i]);
  return ((const short*)p)[i];
}

// ---- fp32 small arena offsets (floats) ----
#define F_X     0
#define F_WE    6400
#define F_BE    7424
#define F_LNW   7936
#define F_LNB   9984
#define F_CW    12032
#define F_CB    28416
#define F_BDT   32512
#define F_ALOG  36608
#define F_D     102144
#define F_FNW   106240
#define F_FNB   106752
#define F_TOT   107264

__device__ const int f_off[13] = {F_X,F_WE,F_BE,F_LNW,F_LNB,F_CW,F_CB,F_BDT,
                                  F_ALOG,F_D,F_FNW,F_FNB,F_TOT};

// ---- bf16 weight arena offsets (shorts) ----
#define B_WIN    0
#define B_WXP    4194304
#define B_WDT    4456448
#define B_WOUT   4587520
#define B_WHEAD  6684672
#define B_TOT    6787072

struct Ps {
  const void* in[17];
  void* out;
  float* fA; short* wB;
  float* res; float* hbuf; float* xdb;
  ushort* hn; ushort* u; ushort* y; ushort* xc; ushort* z;
  int gridN;
};

#define SMEM_BYTES 33024

// ================= device phase bodies (shared by coop + fallback) =============

__device__ __forceinline__ void d_convert(const Ps& p, int base, int stride) {
  bool f32 = probe_is_f32(p.in[3]);
  const int total = F_TOT + B_TOT;
  for (int idx = base; idx < total; idx += stride) {
    if (idx < F_TOT) {
      const void* ps[12] = {p.in[0],p.in[1],p.in[2],p.in[3],p.in[4],p.in[6],
                            p.in[7],p.in[10],p.in[11],p.in[12],p.in[14],p.in[15]};
      int t = 0;
      while (idx >= f_off[t + 1]) ++t;
      p.fA[idx] = ld_in(ps[t], idx - f_off[t], f32);
    } else {
      int j = idx - F_TOT;
      short v;
      if (j < B_WXP)        v = ld_inb(p.in[5],  j,           f32);
      else if (j < B_WDT)   v = ld_inb(p.in[8],  j - B_WXP,   f32);
      else if (j < B_WOUT)  v = ld_inb(p.in[9],  j - B_WDT,   f32);
      else if (j < B_WHEAD) v = ld_inb(p.in[13], j - B_WOUT,  f32);
      else                  v = ld_inb(p.in[16], j - B_WHEAD, f32);
      p.wB[j] = v;
    }
  }
}

__device__ __forceinline__ float block_sum(float v, float* sh) {
  #pragma unroll
  for (int o = 32; o > 0; o >>= 1) v += __shfl_down(v, o, 64);
  int t = threadIdx.x;
  if ((t & 63) == 0) sh[t >> 6] = v;
  __syncthreads();
  if (t == 0) sh[4] = sh[0] + sh[1] + sh[2] + sh[3];
  __syncthreads();
  return sh[4];
}

__device__ __forceinline__ void d_norm(const Ps& p, float* sh, int row,
    const float* w, const float* b, int first, int rms, int embed) {
  int t = threadIdx.x;
  float* hp = p.hbuf + (size_t)row * DMdl;
  float* rp = p.res + (size_t)row * DMdl;
  float v0, v1;
  if (embed) {
    float x0 = p.fA[F_X + row * 2], x1 = p.fA[F_X + row * 2 + 1];
    v0 = x0 * p.fA[F_WE + t * 2] + x1 * p.fA[F_WE + t * 2 + 1] + p.fA[F_BE + t];
    v1 = x0 * p.fA[F_WE + (t + 256) * 2] + x1 * p.fA[F_WE + (t + 256) * 2 + 1]
         + p.fA[F_BE + t + 256];
  } else {
    v0 = hp[t]; v1 = hp[t + 256];
  }
  hp[t] = 0.f; hp[t + 256] = 0.f;
  if (!first) { v0 += rp[t]; v1 += rp[t + 256]; }
  rp[t] = v0; rp[t + 256] = v1;
  float mean = 0.f;
  if (!rms) mean = block_sum(v0 + v1, sh) * (1.f / DMdl);
  float d0 = v0 - mean, d1 = v1 - mean;
  float var = block_sum(d0 * d0 + d1 * d1, sh) * (1.f / DMdl);
  float inv = rsqrtf(var + 1e-5f);
  bf16* op = (bf16*)p.hn + (size_t)row * DMdl;
  op[t]       = __float2bfloat16(d0 * inv * w[t]       + b[t]);
  op[t + 256] = __float2bfloat16(d1 * inv * w[t + 256] + b[t + 256]);
  __syncthreads();
}

__device__ __forceinline__ void async16(const short* g, short* l) {
  __builtin_amdgcn_global_load_lds(
      (const __attribute__((address_space(1))) void*)g,
      (__attribute__((address_space(3))) void*)l, 16, 0, 0);
}

// one GEMM tile; v in [0, nbx*BANDG*SPLITK)
template<int OM, int SPLITK>
__device__ __forceinline__ void d_gemm_tile(const Ps& p, char* sm, int v,
    const short* __restrict__ A, const short* __restrict__ B,
    void* __restrict__ C, void* __restrict__ C2, int N, int K, int act_col,
    int nbx) {
  int L = v % (nbx * BANDG);
  int ksl = v / (nbx * BANDG);
  int xcd = L & 7, w = L >> 3;
  int band = xcd + 8 * (w / nbx);
  int col = w - (w / nbx) * nbx;
  if (band >= NBY) return;
  int bm = band * 128, bn = col * 128;

  short* As = (short*)sm;
  short* Bs = (short*)(sm + 16384);

  int kLen = K / SPLITK;
  int kBeg = ksl * kLen;

  int t = threadIdx.x;
  int lane = t & 63;
  int wave = t >> 6;
  int wm = wave >> 1, wn = wave & 1;

  int ci0 = t, ci1 = 256 + t;
  int r0 = ci0 >> 2, c0 = ci0 & 3;
  int r1 = ci1 >> 2, c1 = ci1 & 3;
  int cs0 = c0 ^ (r0 & 3) ^ ((r0 >> 2) & 3);
  int cs1 = c1 ^ (r1 & 3) ^ ((r1 >> 2) & 3);
  const short* gA0 = A + (size_t)(bm + r0) * K + kBeg + cs0 * 8;
  const short* gA1 = A + (size_t)(bm + r1) * K + kBeg + cs1 * 8;
  int rb0 = bn + r0; if (rb0 >= N) rb0 = N - 1;
  int rb1 = bn + r1; if (rb1 >= N) rb1 = N - 1;
  const short* gB0 = B + (size_t)rb0 * K + kBeg + cs0 * 8;
  const short* gB1 = B + (size_t)rb1 * K + kBeg + cs1 * 8;
  int lo0 = ci0 * 8, lo1 = ci1 * 8;

  f32x4 acc[4][4];
  #pragma unroll
  for (int i = 0; i < 4; ++i)
    #pragma unroll
    for (int j = 0; j < 4; ++j) acc[i][j] = (f32x4){0.f, 0.f, 0.f, 0.f};

  int quad = lane >> 4;
  int r15 = lane & 15;
  int slot = quad ^ (r15 & 3) ^ ((r15 >> 2) & 3);

  int nIter = kLen >> 5;
  async16(gA0, &As[lo0]); async16(gA1, &As[lo1]);
  async16(gB0, &Bs[lo0]); async16(gB1, &Bs[lo1]);
  gA0 += 32; gA1 += 32; gB0 += 32; gB1 += 32;

  for (int it = 0; it < nIter; ++it) {
    int cur = (it & 1) * 4096, nxt = 4096 - cur;
    __syncthreads();
    if (it + 1 < nIter) {
      async16(gA0, &As[nxt + lo0]); async16(gA1, &As[nxt + lo1]);
      async16(gB0, &Bs[nxt + lo0]); async16(gB1, &Bs[nxt + lo1]);
      gA0 += 32; gA1 += 32; gB0 += 32; gB1 += 32;
    }
    short8 af[4], bf[4];
    #pragma unroll
    for (int i = 0; i < 4; ++i) {
      int rowa = wm * 64 + i * 16 + r15;
      int rowb = wn * 64 + i * 16 + r15;
      af[i] = *(const short8*)&As[cur + rowa * 32 + slot * 8];
      bf[i] = *(const short8*)&Bs[cur + rowb * 32 + slot * 8];
    }
    #pragma unroll
    for (int i = 0; i < 4; ++i)
      #pragma unroll
      for (int j = 0; j < 4; ++j)
        acc[i][j] = __builtin_amdgcn_mfma_f32_16x16x32_bf16(af[i], bf[j], acc[i][j], 0, 0, 0);
  }
  __syncthreads();

  bool f32o = true;
  if (OM == 1) f32o = probe_is_f32(p.in[3]);
  #pragma unroll
  for (int i = 0; i < 4; ++i) {
    int m0 = bm + wm * 64 + i * 16 + quad * 4;
    #pragma unroll
    for (int j = 0; j < 4; ++j) {
      int n = bn + wn * 64 + j * 16 + r15;
      if (n >= N) continue;
      #pragma unroll
      for (int r = 0; r < 4; ++r) {
        float vv = acc[i][j][r];
        size_t mrow = (size_t)(m0 + r);
        if (OM == 3) {
          if (n < act_col) {
            ((bf16*)C)[mrow * act_col + n] = __float2bfloat16(vv);
          } else {
            vv = vv / (1.f + __expf(-vv));
            ((bf16*)C2)[mrow * act_col + (n - act_col)] = __float2bfloat16(vv);
          }
          continue;
        }
        size_t off = mrow * N + n;
        if (OM == 0 && SPLITK > 1) atomicAdd((float*)C + off, vv);
        else if (OM == 1 && !f32o) ((bf16*)C)[off] = __float2bfloat16(vv);
        else ((float*)C)[off] = vv;
      }
    }
  }
}

__device__ __forceinline__ void d_conv(const Ps& p, int lay, int base, int stride) {
  for (int idx = base; idx < MROWS * 16; idx += stride)
    ((f32x4*)p.xdb)[idx] = (f32x4){0.f, 0.f, 0.f, 0.f};
  const float* cw = p.fA + F_CW + lay * DIn * 4;
  for (int idx = base; idx < MROWS * (DIn / 2); idx += stride) {
    int pp = idx & (DIn / 2 - 1);
    int m = idx >> 9;
    int l = m % LSq, bb = m / LSq;
    int d = pp * 2;
    float a0 = p.fA[F_CB + lay * DIn + d];
    float a1 = p.fA[F_CB + lay * DIn + d + 1];
    #pragma unroll
    for (int k = 0; k < 4; ++k) {
      int ls = l + k - 3;
      if (ls >= 0) {
        uint xv = *(const uint*)&p.xc[(size_t)(bb * LSq + ls) * DIn + d];
        a0 += lo_f(xv) * cw[d * 4 + k];
        a1 += hi_f(xv) * cw[(d + 1) * 4 + k];
      }
    }
    a0 = a0 / (1.f + __expf(-a0));
    a1 = a1 / (1.f + __expf(-a1));
    *(uint*)&p.u[(size_t)idx * 2] = bbits(a0) | (bbits(a1) << 16);
  }
}

// one scan task; v in [0, 1024)
__device__ __forceinline__ void d_scan_task(const Ps& p, char* sm, int lay, int v) {
  float* sX   = (float*)sm;              // 50*68 f32
  float* sDUZ = (float*)(sm + 13600);    // 50*48 f32
  float* sY   = (float*)(sm + 23200);    // 50*16 f32
  float* sD   = (float*)(sm + 26400);    // 16 f32
  const short* wdt = p.wB + B_WDT;
  int tid = threadIdx.x;
  int n = tid & 15;
  int g = tid >> 4;
  int xcd = v & 7, w = v >> 3;
  int dblk = xcd * 8 + (w & 7);
  int bb = w >> 3;
  int d0 = dblk * 16;
  int d  = d0 + g;
  float Ac = -__expf(p.fA[F_ALOG + lay * DIn * DSn + d * DSn + n]);
  if (tid < 16) sD[tid] = p.fA[F_D + lay * DIn + d0 + tid];
  float wf[DRn];
  {
    const uint* wp = (const uint*)(wdt + (size_t)lay * (DIn * DRn) + (d0 + n) * DRn);
    #pragma unroll
    for (int k = 0; k < 16; ++k) {
      uint wv = wp[k];
      wf[2 * k] = lo_f(wv); wf[2 * k + 1] = hi_f(wv);
    }
  }
  float bd = p.fA[F_BDT + lay * DIn + d0 + n];
  float h = 0.f;

  f32x4 rX[4]; uint rU[2], rZ[2];
  auto load_regs = [&](int c0) {
    int row0 = bb * LSq + c0;
    const f32x4* xp = (const f32x4*)(p.xdb + (size_t)row0 * 64);
    #pragma unroll
    for (int k = 0; k < 4; ++k) {
      int i = k * 256 + tid;
      if (i < TCH * 16) rX[k] = xp[i];
    }
    #pragma unroll
    for (int k = 0; k < 2; ++k) {
      int i = k * 256 + tid;
      if (i < TCH * 8) {
        int s = i >> 3, jp = i & 7;
        rU[k] = *(const uint*)&p.u[(size_t)(row0 + s) * DIn + d0 + jp * 2];
        rZ[k] = *(const uint*)&p.z[(size_t)(row0 + s) * DIn + d0 + jp * 2];
      }
    }
  };

  load_regs(0);
  for (int c = 0; c < LSq / TCH; ++c) {
    __syncthreads();
    #pragma unroll
    for (int k = 0; k < 4; ++k) {
      int i = k * 256 + tid;
      if (i < TCH * 16) {
        int s = i >> 4, q = i & 15;
        *(f32x4*)&sX[s * XSTR + q * 4] = rX[k];
      }
    }
    #pragma unroll
    for (int k = 0; k < 2; ++k) {
      int i = k * 256 + tid;
      if (i < TCH * 8) {
        int s = i >> 3, jp = i & 7;
        sDUZ[s * 48 + 16 + jp * 2]     = lo_f(rU[k]);
        sDUZ[s * 48 + 16 + jp * 2 + 1] = hi_f(rU[k]);
        sDUZ[s * 48 + 32 + jp * 2]     = lo_f(rZ[k]);
        sDUZ[s * 48 + 32 + jp * 2 + 1] = hi_f(rZ[k]);
      }
    }
    if (c + 1 < LSq / TCH) load_regs((c + 1) * TCH);
    __syncthreads();
    #pragma unroll
    for (int k = 0; k < 4; ++k) {
      int i = k * 256 + tid;
      if (i < TCH * 16) {
        int s = i >> 4;
        const float* xs = &sX[s * XSTR];
        float acc = bd;
        #pragma unroll
        for (int r = 0; r < DRn; ++r) acc += wf[r] * xs[r];
        sDUZ[s * 48 + n] = (acc > 15.f) ? acc : __logf(1.f + __expf(acc));
      }
    }
    __syncthreads();
    #pragma unroll 2
    for (int s = 0; s < TCH; ++s) {
      float Bv  = sX[s * XSTR + 32 + n];
      float Cv  = sX[s * XSTR + 48 + n];
      float dtv = sDUZ[s * 48 + g];
      float uv  = sDUZ[s * 48 + 16 + g];
      float dA = __expf(dtv * Ac);
      h = fmaf(dA, h, dtv * Bv * uv);
      float cc = h * Cv;
      cc = dpp_add<0xB1>(cc);
      cc = dpp_add<0x4E>(cc);
      cc = dpp_add<0x141>(cc);
      cc = dpp_add<0x140>(cc);
      if (n == 0) sY[s * 16 + g] = cc;
    }
    __syncthreads();
    int row0 = bb * LSq + c * TCH;
    for (int i = tid; i < TCH * 16; i += 256) {
      int s = i >> 4, j = i & 15;
      float uv = sDUZ[s * 48 + 16 + j];
      float sz = sDUZ[s * 48 + 32 + j];
      ((bf16*)p.y)[(size_t)(row0 + s) * DIn + d0 + j] =
          __float2bfloat16((sY[i] + sD[j] * uv) * sz);
    }
  }
  __syncthreads();
}

// ================= cooperative persistent kernel =================
__global__ void k_mamba(Ps p) {
  cg::grid_group grid = cg::this_grid();
  __shared__ __align__(16) char sm[SMEM_BYTES];
  const int gN = p.gridN;

  d_convert(p, blockIdx.x * 256 + threadIdx.x, gN * 256);
  grid.sync();

  for (int i = 0; i < NLa; ++i) {
    for (int row = blockIdx.x; row < MROWS; row += gN)
      d_norm(p, (float*)sm, row, p.fA + F_LNW + i * DMdl,
             p.fA + F_LNB + i * DMdl, (i == 0) ? 1 : 0, 0, (i == 0) ? 1 : 0);
    grid.sync();
    for (int v = blockIdx.x; v < 16 * BANDG; v += gN) {
      __syncthreads();
      d_gemm_tile<3, 1>(p, sm, v, (const short*)p.hn,
                        p.wB + B_WIN + (size_t)i * 2 * DIn * DMdl,
                        p.xc, p.z, 2 * DIn, DMdl, DIn, 16);
    }
    grid.sync();
    d_conv(p, i, blockIdx.x * 256 + threadIdx.x, gN * 256);
    grid.sync();
    for (int v = blockIdx.x; v < 1 * BANDG * 8; v += gN) {
      __syncthreads();
      d_gemm_tile<0, 8>(p, sm, v, (const short*)p.u,
                        p.wB + B_WXP + (size_t)i * 64 * DIn,
                        p.xdb, nullptr, 64, DIn, 0, 1);
    }
    grid.sync();
    for (int v = blockIdx.x; v < SCANV; v += gN)
      d_scan_task(p, sm, i, v);
    grid.sync();
    for (int v = blockIdx.x; v < 4 * BANDG * 2; v += gN) {
      __syncthreads();
      d_gemm_tile<0, 2>(p, sm, v, (const short*)p.y,
                        p.wB + B_WOUT + (size_t)i * DMdl * DIn,
                        p.hbuf, nullptr, DMdl, DIn, 0, 4);
    }
    grid.sync();
  }

  for (int row = blockIdx.x; row < MROWS; row += gN)
    d_norm(p, (float*)sm, row, p.fA + F_FNW, p.fA + F_FNB, 0, 1, 0);
  grid.sync();
  for (int v = blockIdx.x; v < 2 * BANDG; v += gN) {
    __syncthreads();
    d_gemm_tile<1, 1>(p, sm, v, (const short*)p.hn, p.wB + B_WHEAD,
                      p.out, nullptr, CCl, DMdl, 0, 2);
  }
}

// ================= fallback wrappers (r12 structure) =================
__global__ __launch_bounds__(256) void k_convert_g(Ps p) {
  d_convert(p, blockIdx.x * 256 + threadIdx.x, gridDim.x * 256);
}
__global__ __launch_bounds__(256) void k_norm_g(Ps p, int lwoff, int lboff,
                                                int first, int rms, int embed) {
  __shared__ float sh[8];
  d_norm(p, sh, blockIdx.x, p.fA + lwoff, p.fA + lboff, first, rms, embed);
}
template<int OM, int SPLITK>
__global__ __launch_bounds__(256) void k_mfma_g(Ps p, const short* A,
    const short* B, void* C, void* C2, int N, int K, int act_col, int nbx) {
  __shared__ __align__(16) char sm[32768];
  int v = blockIdx.x + blockIdx.y * (nbx * BANDG);
  d_gemm_tile<OM, SPLITK>(p, sm, v, A, B, C, C2, N, K, act_col, nbx);
}
__global__ __launch_bounds__(256) void k_conv_g(Ps p, int lay) {
  d_conv(p, lay, blockIdx.x * 256 + threadIdx.x, gridDim.x * 256);
}
__global__ __launch_bounds__(256) void k_scan_g(Ps p, int lay) {
  __shared__ __align__(16) char sm[26464];
  d_scan_task(p, sm, lay, blockIdx.x);
}

extern "C" void kernel_launch(void* const* d_in, const int* in_sizes, int n_in,
                              void* d_out, int out_size, void* d_ws, size_t ws_size,
                              hipStream_t stream) {
  Ps p;
  for (int i = 0; i < 17; ++i) p.in[i] = d_in[i];
  p.out = d_out;
  p.fA = (float*)d_ws;
  p.wB = (short*)(p.fA + F_TOT);
  float* acts = (float*)(p.wB + B_TOT);
  p.res  = acts;
  p.hbuf = p.res  + (size_t)MROWS * DMdl;
  p.xdb  = p.hbuf + (size_t)MROWS * DMdl;
  p.hn = (ushort*)(p.xdb + (size_t)MROWS * 64);
  p.u  = p.hn + (size_t)MROWS * DMdl;
  p.y  = p.u  + (size_t)MROWS * DIn;
  p.xc = p.y  + (size_t)MROWS * DIn;
  p.z  = p.xc + (size_t)MROWS * DIn;

  // occupancy-derived cooperative grid (pure query — capture-safe)
  int nb = 0;
  hipError_t qe = hipOccupancyMaxActiveBlocksPerMultiprocessor(&nb, k_mamba, 256, 0);
  int gridN = (qe == hipSuccess && nb > 0) ? (nb * 256 > 1024 ? 1024 : nb * 256) : 0;

  bool done = false;
  if (gridN >= 256) {
    p.gridN = gridN;
    void* args[] = { &p };
    if (hipLaunchCooperativeKernel((void*)k_mamba, dim3(gridN), dim3(256),
                                   args, 0, stream) == hipSuccess)
      done = true;
  }
  if (done) return;

  // ---------- fallback: r12 multi-kernel sequence ----------
  k_convert_g<<<(F_TOT + B_TOT + 255) / 256, 256, 0, stream>>>(p);
  for (int i = 0; i < NLa; ++i) {
    k_norm_g<<<MROWS, 256, 0, stream>>>(p, F_LNW + i * DMdl, F_LNB + i * DMdl,
                                        (i == 0) ? 1 : 0, 0, (i == 0) ? 1 : 0);
    k_mfma_g<3, 1><<<dim3(16 * BANDG, 1), 256, 0, stream>>>(
        p, (const short*)p.hn, p.wB + B_WIN + (size_t)i * 2 * DIn * DMdl,
        p.xc, p.z, 2 * DIn, DMdl, DIn, 16);
    k_conv_g<<<(MROWS * (DIn / 2) + 255) / 256, 256, 0, stream>>>(p, i);
    k_mfma_g<0, 8><<<dim3(1 * BANDG, 8), 256, 0, stream>>>(
        p, (const short*)p.u, p.wB + B_WXP + (size_t)i * 64 * DIn,
        p.xdb, nullptr, 64, DIn, 0, 1);
    k_scan_g<<<SCANV, 256, 0, stream>>>(p, i);
    k_mfma_g<0, 2><<<dim3(4 * BANDG, 2), 256, 0, stream>>>(
        p, (const short*)p.y, p.wB + B_WOUT + (size_t)i * DMdl * DIn,
        p.hbuf, nullptr, DMdl, DIn, 0, 4);
  }
  k_norm_g<<<MROWS, 256, 0, stream>>>(p, F_FNW, F_FNB, 0, 1, 0);
  k_mfma_g<1, 1><<<dim3(2 * BANDG, 1), 256, 0, stream>>>(
      p, (const short*)p.hn, p.wB + B_WHEAD, p.out, nullptr, CCl, DMdl, 0, 2);
}